// Round 7
// baseline (771.223 us; speedup 1.0000x reference)
//
#include <hip/hip_runtime.h>

#define B 64
#define NORI 510
#define NJNT 501
#define DM 512
#define HID 128
#define NG 512

constexpr long EMB0 = (long)B * NORI;                    // existence size
constexpr long RD0  = EMB0 + (long)B * NORI * DM;        // right_direc offset
constexpr long JN0  = RD0 + (long)B * NORI * 2;          // joint offset

// sync[] counters, each padded to its own 256B line (64 ints apart).
#define SY_TICKET 0
#define SY_CMB 1    // +l, l=0..6 : combine-level-l finished tasks
#define SY_XP  8    // +l, l=1..7 : xp-level-l finished tasks
#define SY_H   16   // +l, l=0..7 : LSTM chains finished (8 per level)
#define NTASK 4121
__device__ __forceinline__ int* syncp(int* s, int idx) { return s + idx * 64; }

typedef __attribute__((ext_vector_type(8))) short short8;
typedef __attribute__((ext_vector_type(4))) float f32x4;
typedef __attribute__((ext_vector_type(4))) unsigned short u16x4;
typedef __attribute__((ext_vector_type(4))) unsigned int u32x4;

__device__ __forceinline__ float bf2f(unsigned short u) {
  unsigned int x = ((unsigned int)u) << 16;
  return __builtin_bit_cast(float, x);
}
__device__ __forceinline__ unsigned short f2bf(float f) {
  unsigned int x = __builtin_bit_cast(unsigned int, f);
  unsigned int r = (x + 0x7FFFu + ((x >> 16) & 1u)) >> 16;
  return (unsigned short)r;
}
__device__ __forceinline__ float sigm(float x) { return 1.f / (1.f + __expf(-x)); }
__device__ __forceinline__ float tanh_(float x) { return 2.f / (1.f + __expf(-2.f * x)) - 1.f; }
__device__ __forceinline__ float e2(float x) { return __builtin_amdgcn_exp2f(x); }
__device__ __forceinline__ float rcp_(float x) { return __builtin_amdgcn_rcpf(x); }
#define L2E 1.4426950408889634f

__device__ __forceinline__ void ld_lds16(const void* g, void* l) {
  __builtin_amdgcn_global_load_lds(
      (const __attribute__((address_space(1))) unsigned int*)g,
      (__attribute__((address_space(3))) unsigned int*)l, 16, 0, 0);
}

__device__ __forceinline__ float in_load(const void* p, long i, int fm) {
  return fm ? bf2f(((const unsigned short*)p)[i]) : ((const float*)p)[i];
}
__device__ __forceinline__ float out_loadf(const void* p, long i, int fm) {
  return fm ? bf2f(((const unsigned short*)p)[i]) : ((const float*)p)[i];
}
__device__ __forceinline__ void out_storef(void* p, long i, float v, int fm) {
  if (fm) ((unsigned short*)p)[i] = f2bf(v);
  else    ((float*)p)[i] = v;
}
// non-temporal variant: keeps the L2 dirty set small so the agent-release
// L2-writeback walks (one per task) stay cheap.
__device__ __forceinline__ void out_storent(void* p, long i, float v, int fm) {
  if (fm) __builtin_nontemporal_store(f2bf(v), (unsigned short*)p + i);
  else    __builtin_nontemporal_store(v, (float*)p + i);
}
__device__ __forceinline__ unsigned short cvbf(const void* p, long i, int fm) {
  return fm ? ((const unsigned short*)p)[i] : f2bf(((const float*)p)[i]);
}

// gate scale: gates i,f,o pre-scaled by -log2(e); gate g by +2*log2(e).
__device__ __forceinline__ float gsc(int gate) {
  return (gate == 2) ? (2.f * L2E) : (-L2E);
}

__device__ __forceinline__ int bmode(const void* p) {
  unsigned int u = *(const unsigned int*)p;
  if (u == 1u) return 1;
  if (u == 0x3F800000u) return 2;
  if (u == 0x00003F80u || u == 0x3F803F80u) return 3;
  return 0;
}
__device__ __forceinline__ bool loadb(const void* p, long i, int m) {
  switch (m) {
    case 1: return ((const int*)p)[i] != 0;
    case 2: return ((const float*)p)[i] != 0.f;
    case 3: return ((const unsigned short*)p)[i] != 0;
    default: return ((const unsigned char*)p)[i] != 0;
  }
}

// ---- device-scope flag sync (r5-verified): ONE relaxed spinner per block,
// one ACQUIRE on success, ~20ms watchdog.
__device__ __forceinline__ void acquire_wait(int* f, int target) {
  if (threadIdx.x == 0) {
    unsigned long t0 = __builtin_amdgcn_s_memrealtime();
    while (__hip_atomic_load(f, __ATOMIC_RELAXED, __HIP_MEMORY_SCOPE_AGENT) < target) {
      __builtin_amdgcn_s_sleep(8);
      if (__builtin_amdgcn_s_memrealtime() - t0 > 2000000UL) break;
    }
    (void)__hip_atomic_load(f, __ATOMIC_ACQUIRE, __HIP_MEMORY_SCOPE_AGENT);
  }
  __syncthreads();
}
__device__ __forceinline__ void release_add(int* f) {
  __hip_atomic_fetch_add(f, 1, __ATOMIC_RELEASE, __HIP_MEMORY_SCOPE_AGENT);
}

// ---- detect f32 vs bf16 float inputs ----
__global__ void k_detect(const unsigned int* raw, int* flag) {
  __shared__ int cnt[256];
  int t = threadIdx.x;
  unsigned int u = raw[(long)t * 16001];
  unsigned int e = (u >> 8) & 0x7F;
  cnt[t] = (e >= 0x34 && e <= 0x44) ? 1 : 0;
  __syncthreads();
  for (int d = 128; d; d >>= 1) { if (t < d) cnt[t] += cnt[t + d]; __syncthreads(); }
  if (t == 0) flag[0] = (cnt[0] >= 128) ? 1 : 0;
}

// ---- ALL prep work in one launch + sync-flag zeroing ----
__global__ void k_prep_all(const void* ue, const void* sright, const void* sjoint, const void* exist,
                           const void* wih_f, const void* wih_b, const void* whh_f, const void* whh_b,
                           const void* w_cmb, const void* w_cnv,
                           const void* b_f, const void* b_b, const void* b_cnv, const void* b_ori,
                           const void* b_jnt, const void* b_cmb, const void* w_ori, const void* w_jnt,
                           const void* h0, const void* c0,
                           unsigned short* d_wihf, unsigned short* d_wihb,
                           unsigned short* d_whhf, unsigned short* d_whhb,
                           unsigned short* wcmbT, unsigned short* wc0T, unsigned short* wc1T,
                           float* d_bf, float* d_bb, float* d_bcnv, float* d_bori, float* d_bjnt,
                           float* d_bcmb, float* d_wori, float* d_wjnt, float* d_h0, float* d_c0,
                           void* outp, unsigned short* embw,
                           int* lhsA, int* rhsA, int* jntA,
                           const int* flag, int* sync) {
  __shared__ int sc[256];
  int fm = *flag;
  int bx = blockIdx.x, t = threadIdx.x;
  if (bx < 2560) {                       // wih/whh -> bf16, pre-scaled per gate
    int i = bx * 256 + t;
    if (i < 262144) {
      int row = i >> 9;
      d_wihf[i] = f2bf(in_load(wih_f, i, fm) * gsc(row >> 7));
    } else if (i < 524288) {
      int k = i - 262144; int row = k >> 9;
      d_wihb[k] = f2bf(in_load(wih_b, k, fm) * gsc(row >> 7));
    } else if (i < 589824) {
      int k = i - 524288; int row = k >> 7;
      d_whhf[k] = f2bf(in_load(whh_f, k, fm) * gsc(row >> 7));
    } else if (i < 655360) {
      int k = i - 589824; int row = k >> 7;
      d_whhb[k] = f2bf(in_load(whh_b, k, fm) * gsc(row >> 7));
    }
  } else if (bx < 4608) {                // w_cmb^T (1024x512)
    int i = (bx - 2560) * 256 + t;
    int r = i / 512, c = i - r * 512;
    wcmbT[(long)c * 1024 + r] = f2bf(in_load(w_cmb, i, fm));
  } else if (bx < 5120) {                // w_cnv[0]^T (512x256)
    int i = (bx - 4608) * 256 + t;
    int r = i / 256, c = i - r * 256;
    wc0T[(long)c * 512 + r] = f2bf(in_load(w_cnv, i, fm));
  } else if (bx < 5632) {                // w_cnv[1]^T
    int i = (bx - 5120) * 256 + t;
    int r = i / 256, c = i - r * 256;
    wc1T[(long)c * 512 + r] = f2bf(in_load(w_cnv, (long)512 * 256 + i, fm));
  } else if (bx < 5645) {                // small f32 params (b_f/b_b gate-scaled)
    int i = (bx - 5632) * 256 + t;
    if (i < 512)       d_bf[i] = in_load(b_f, i, fm) * gsc(i >> 7);
    else if (i < 1024) { int k = i - 512; d_bb[k] = in_load(b_b, k, fm) * gsc(k >> 7); }
    else if (i < 1280) d_bcnv[i - 1024] = in_load(b_cnv, i - 1024, fm);
    else if (i < 1282) d_bori[i - 1280] = in_load(b_ori, i - 1280, fm);
    else if (i < 1283) d_bjnt[i - 1282] = in_load(b_jnt, i - 1282, fm);
    else if (i < 1795) d_bcmb[i - 1283] = in_load(b_cmb, i - 1283, fm);
    else if (i < 2307) d_wori[i - 1795] = in_load(w_ori, i - 1795, fm);
    else if (i < 2563) d_wjnt[i - 2307] = in_load(w_jnt, i - 2307, fm);
    else if (i < 2819) d_h0[i - 2563] = in_load(h0, i - 2563, fm);
    else if (i < 3075) d_c0[i - 2819] = in_load(c0, i - 2819, fm);
  } else if (bx < 5773) {                // existence_out = 1
    int i = (bx - 5645) * 256 + t;
    if (i < B * NORI) out_storef(outp, i, 1.0f, fm);
  } else if (bx < 38541) {               // emb level-0 init
    long i = (long)(bx - 5773) * 256 + t;
    int bb = (int)(i >> 17);
    int p  = (int)((i >> 9) & 255);
    int d  = (int)(i & 511);
    float v = in_load(ue, i, fm);
    long row = (long)(bb * NORI + p) * DM + d;
    out_storef(outp, EMB0 + row, v, fm);
    embw[row] = f2bf(v);
  } else if (bx < 38989) {               // split/merge, all 7 levels
    int idx = bx - 38541;
    int level = idx >> 6, b = idx & 63;
    int n = 256 >> level, n2 = n >> 1;
    int offr = 512 - (512 >> level);
    int offj = offr - level;
    int mr = bmode(sright), mj = bmode(sjoint), me = bmode(exist);
    int* lhs = lhsA + level * B * 128;
    int* rhs = rhsA + level * B * 128;
    int* jnt = jntA + level * B * 128;
    int i = t;
    bool pj = false, ns = false;
    if (i < n) {
      bool ri   = loadb(sright, (long)b * NORI + offr + i, mr);
      bool rim1 = (i > 0)     ? loadb(sright, (long)b * NORI + offr + i - 1, mr) : false;
      bool rip1 = (i + 1 < n) ? loadb(sright, (long)b * NORI + offr + i + 1, mr) : false;
      bool ji   = (i < n - 1) ? loadb(sjoint, (long)b * NJNT + offj + i, mj) : false;
      bool jim1 = (i > 0)     ? loadb(sjoint, (long)b * NJNT + offj + i - 1, mj) : false;
      pj = (i < n - 1) && ri && !rip1 && ji;
      bool rhs_is = (i > 0) && rim1 && !ri && jim1;
      bool ex = (level == 0) ? loadb(exist, (long)b * 256 + i, me) : true;
      ns = ex && !rhs_is;
    }
    sc[i] = (i < n && ns) ? 1 : 0;
    if (i < n2) { lhs[b * n2 + i] = 0; rhs[b * n2 + i] = 0; jnt[b * n2 + i] = 0; }
    __syncthreads();
    for (int d = 1; d < 256; d <<= 1) {
      int v = sc[i];
      int u = (i >= d) ? sc[i - d] : 0;
      __syncthreads();
      sc[i] = v + u;
      __syncthreads();
    }
    if (i < n) {
      int nid = sc[i] - 1;
      if (ns && nid >= 0 && nid < n2) lhs[b * n2 + nid] = i;
      if (pj && nid >= 0 && nid < n2) { rhs[b * n2 + nid] = i + 1; jnt[b * n2 + nid] = 1; }
    }
  } else {                               // zero padded sync counters (4096 ints)
    for (int i = t; i < 4096; i += 256) sync[i] = 0;
  }
}

// ================= task bodies =================

// xp GEMM: 2 x 64x64 tiles (512 threads, 256 per subtile), pipelined k-loop
__device__ void body_xp(char* smem_, int tid, int tile0, int level,
                        const unsigned short* __restrict__ embbf,
                        const unsigned short* __restrict__ wihf, const unsigned short* __restrict__ wihb,
                        const float* __restrict__ bfp, const float* __restrict__ bbp,
                        unsigned short* __restrict__ xpf, unsigned short* __restrict__ xpb) {
  int sub = tid >> 8, t5 = tid & 255;
  int tile = tile0 + sub;
  unsigned short (*As)[40] = (unsigned short (*)[40])(smem_ + sub * 10240);
  unsigned short (*Bs)[40] = (unsigned short (*)[40])(smem_ + sub * 10240 + 5120);
  int nb = tile & 15, mb = tile >> 4;
  const unsigned short* Bt = (nb < 8) ? wihf : wihb;
  const float* bias = (nb < 8) ? bfp : bbp;
  unsigned short* out = (nb < 8) ? xpf : xpb;
  int m0 = mb * 64, n0 = (nb & 7) * 64;
  int nl = 256 >> level, off = 512 - (512 >> level), sh = 8 - level;
  int lane = t5 & 63, wv = t5 >> 6;
  int col = lane & 15, quad = lane >> 4;
  int mq = (wv >> 1) * 32, nq = (wv & 1) * 32;
  int sr = t5 >> 2, sc = (t5 & 3) * 8;
  int mi = m0 + sr;
  int rb = mi >> sh, rp = mi & (nl - 1);
  const unsigned short* ap = &embbf[((long)(rb * NORI + off + rp)) * DM + sc];
  const unsigned short* bp = &Bt[(long)(n0 + sr) * DM + sc];
  f32x4 zero = {0.f, 0.f, 0.f, 0.f};
  f32x4 acc[2][2];
  acc[0][0] = zero; acc[0][1] = zero; acc[1][0] = zero; acc[1][1] = zero;
  u32x4 av = *(const u32x4*)(ap);
  u32x4 bv = *(const u32x4*)(bp);
  for (int k0 = 0; k0 < DM; k0 += 32) {
    __syncthreads();
    *(u32x4*)&As[sr][sc] = av;
    *(u32x4*)&Bs[sr][sc] = bv;
    __syncthreads();
    if (k0 + 32 < DM) {
      av = *(const u32x4*)(ap + k0 + 32);
      bv = *(const u32x4*)(bp + k0 + 32);
    }
    short8 a0 = *(const short8*)&As[mq + col][quad * 8];
    short8 a1 = *(const short8*)&As[mq + 16 + col][quad * 8];
    short8 b0 = *(const short8*)&Bs[nq + col][quad * 8];
    short8 b1 = *(const short8*)&Bs[nq + 16 + col][quad * 8];
    acc[0][0] = __builtin_amdgcn_mfma_f32_16x16x32_bf16(a0, b0, acc[0][0], 0, 0, 0);
    acc[0][1] = __builtin_amdgcn_mfma_f32_16x16x32_bf16(a0, b1, acc[0][1], 0, 0, 0);
    acc[1][0] = __builtin_amdgcn_mfma_f32_16x16x32_bf16(a1, b0, acc[1][0], 0, 0, 0);
    acc[1][1] = __builtin_amdgcn_mfma_f32_16x16x32_bf16(a1, b1, acc[1][1], 0, 0, 0);
  }
#pragma unroll
  for (int mt = 0; mt < 2; ++mt)
#pragma unroll
    for (int nt = 0; nt < 2; ++nt)
#pragma unroll
      for (int r = 0; r < 4; ++r) {
        int m = m0 + mq + mt * 16 + quad * 4 + r;
        int ob = m >> sh, op = m & (nl - 1);
        int n = n0 + nq + nt * 16 + col;
        __builtin_nontemporal_store(f2bf(acc[mt][nt][r] + bias[n]),
                                    &out[((long)(ob * NORI + off + op)) * NG + n]);
      }
}

// combine GEMM + gated merge: 2 x 64x64 tiles, pipelined k-loop
__device__ void body_cmb(char* smem_, int tid, int tile0, int level,
                         const unsigned short* __restrict__ embbf,
                         const unsigned short* __restrict__ wcmbT,
                         const float* __restrict__ bcmb,
                         const int* __restrict__ lhsA, const int* __restrict__ rhsA,
                         const int* __restrict__ jntA,
                         void* __restrict__ outp, unsigned short* __restrict__ embw, int fm) {
  int n2 = 128 >> level, lg = 7 - level;
  int off = 512 - (512 >> level);
  int off2 = 512 - (256 >> level);
  const int* lhs = lhsA + level * B * 128;
  const int* rhs = rhsA + level * B * 128;
  const int* jntf = jntA + level * B * 128;
  int sub = tid >> 8, t5 = tid & 255;
  int tile = tile0 + sub;
  unsigned short (*As)[40] = (unsigned short (*)[40])(smem_ + sub * 10240);
  unsigned short (*Bs)[40] = (unsigned short (*)[40])(smem_ + sub * 10240 + 5120);
  int nb = tile & 7, mb = tile >> 3;
  int m0 = mb * 64, n0 = nb * 64;
  int lane = t5 & 63, wv = t5 >> 6;
  int col = lane & 15, quad = lane >> 4;
  int mq = (wv >> 1) * 32, nq = (wv & 1) * 32;
  int sr = t5 >> 2, sc = (t5 & 3) * 8;
  int rm = m0 + sr;
  int rb = rm >> lg, rj = rm & (n2 - 1);
  int li = lhs[rb * n2 + rj], ri = rhs[rb * n2 + rj];
  long arowL = ((long)(rb * NORI + off + li)) * DM;
  long arowR = ((long)(rb * NORI + off + ri)) * DM;
  const unsigned short* bp = &wcmbT[(long)(n0 + sr) * 1024 + sc];
  f32x4 zero = {0.f, 0.f, 0.f, 0.f};
  f32x4 acc[2][2];
  acc[0][0] = zero; acc[0][1] = zero; acc[1][0] = zero; acc[1][1] = zero;
  u32x4 av = *(const u32x4*)&embbf[arowL + sc];
  u32x4 bv = *(const u32x4*)(bp);
  for (int k0 = 0; k0 < 1024; k0 += 32) {
    __syncthreads();
    *(u32x4*)&As[sr][sc] = av;
    *(u32x4*)&Bs[sr][sc] = bv;
    __syncthreads();
    int kn = k0 + 32;
    if (kn < 1024) {
      long abase = (kn < 512) ? arowL : arowR;
      av = *(const u32x4*)&embbf[abase + (kn & 511) + sc];
      bv = *(const u32x4*)(bp + kn);
    }
    short8 a0 = *(const short8*)&As[mq + col][quad * 8];
    short8 a1 = *(const short8*)&As[mq + 16 + col][quad * 8];
    short8 b0 = *(const short8*)&Bs[nq + col][quad * 8];
    short8 b1 = *(const short8*)&Bs[nq + 16 + col][quad * 8];
    acc[0][0] = __builtin_amdgcn_mfma_f32_16x16x32_bf16(a0, b0, acc[0][0], 0, 0, 0);
    acc[0][1] = __builtin_amdgcn_mfma_f32_16x16x32_bf16(a0, b1, acc[0][1], 0, 0, 0);
    acc[1][0] = __builtin_amdgcn_mfma_f32_16x16x32_bf16(a1, b0, acc[1][0], 0, 0, 0);
    acc[1][1] = __builtin_amdgcn_mfma_f32_16x16x32_bf16(a1, b1, acc[1][1], 0, 0, 0);
  }
#pragma unroll
  for (int mt = 0; mt < 2; ++mt) {
#pragma unroll
    for (int r = 0; r < 4; ++r) {
      int mm = m0 + mq + mt * 16 + quad * 4 + r;
      int eb = mm >> lg, ej = mm & (n2 - 1);
      int eli = lhs[eb * n2 + ej];
      int eji = jntf[eb * n2 + ej];
      int eri = rhs[eb * n2 + ej];
#pragma unroll
      for (int nt = 0; nt < 2; ++nt) {
        int nn = n0 + nq + nt * 16 + col;
        float g = sigm(acc[mt][nt][r] + bcmb[nn]);
        float lv = out_loadf(outp, EMB0 + ((long)(eb * NORI + off + eli)) * DM + nn, fm);
        float res;
        if (eji) {
          float rv = out_loadf(outp, EMB0 + ((long)(eb * NORI + off + eri)) * DM + nn, fm);
          res = g * lv + (1.f - g) * rv;
        } else res = lv;
        long didx = ((long)(eb * NORI + off2 + ej)) * DM + nn;
        out_storent(outp, EMB0 + didx, res, fm);
        __builtin_nontemporal_store(f2bf(res), &embw[didx]);
      }
    }
  }
}

// joint head: one 64-row x 256-col group, K=1024, fused reduce (512 threads)
__device__ void body_jnt(char* smem_, int tid, int g,
                         const unsigned short* __restrict__ embbf,
                         const unsigned short* __restrict__ wc0T, const unsigned short* __restrict__ wc1T,
                         const float* __restrict__ bcnv, const float* __restrict__ wjnt,
                         const float* __restrict__ bjnt, void* __restrict__ outp, int fm) {
  unsigned short (*As)[40] = (unsigned short (*)[40])smem_;
  unsigned short (*Bs)[40] = (unsigned short (*)[40])(smem_ + 5120);
  float* jlds = (float*)(smem_ + 5120 + 20480);
  const int joffs[8] = {0, 255, 382, 445, 476, 491, 498, 501};
  int w = tid >> 6, lane = tid & 63, col = lane & 15, quad = lane >> 4;
  int mq = (w >> 2) * 32, nq = (w & 3) * 64;
  int sc = (tid & 3) * 8;

  const unsigned short* aptr = embbf;
  if (tid < 256) {
    int jrow = g * 64 + (tid >> 2);
    int b = jrow / 501, jr = jrow - b * 501;
    int l = 0;
    while (l < 6 && jr >= joffs[l + 1]) ++l;
    int t_ = jr - joffs[l];
    int offl = 512 - (512 >> l);
    aptr = embbf + ((long)(b * NORI + offl + t_)) * DM;
  }
  int brow1 = tid >> 2, brow2 = brow1 + 128;

  f32x4 zero = {0.f, 0.f, 0.f, 0.f};
  f32x4 acc[2][4];
#pragma unroll
  for (int mt = 0; mt < 2; ++mt)
#pragma unroll
    for (int nt = 0; nt < 4; ++nt) acc[mt][nt] = zero;

  u32x4 av, bv1, bv2;
  if (tid < 256) av = *(const u32x4*)(aptr + sc);
  bv1 = *(const u32x4*)&wc0T[(long)brow1 * DM + sc];
  bv2 = *(const u32x4*)&wc0T[(long)brow2 * DM + sc];
  for (int kk = 0; kk < 1024; kk += 32) {
    __syncthreads();
    if (tid < 256) *(u32x4*)&As[tid >> 2][sc] = av;
    *(u32x4*)&Bs[brow1][sc] = bv1;
    *(u32x4*)&Bs[brow2][sc] = bv2;
    __syncthreads();
    int kn = kk + 32;
    if (kn < 1024) {
      const unsigned short* Bn = (kn >> 9) ? wc1T : wc0T;
      if (tid < 256) av = *(const u32x4*)(aptr + kn + sc);
      bv1 = *(const u32x4*)&Bn[(long)brow1 * DM + (kn & 511) + sc];
      bv2 = *(const u32x4*)&Bn[(long)brow2 * DM + (kn & 511) + sc];
    }
    short8 a0 = *(const short8*)&As[mq + col][quad * 8];
    short8 a1 = *(const short8*)&As[mq + 16 + col][quad * 8];
#pragma unroll
    for (int nt = 0; nt < 4; ++nt) {
      short8 bfr = *(const short8*)&Bs[nq + nt * 16 + col][quad * 8];
      acc[0][nt] = __builtin_amdgcn_mfma_f32_16x16x32_bf16(a0, bfr, acc[0][nt], 0, 0, 0);
      acc[1][nt] = __builtin_amdgcn_mfma_f32_16x16x32_bf16(a1, bfr, acc[1][nt], 0, 0, 0);
    }
  }
  float part[2][4];
#pragma unroll
  for (int mt = 0; mt < 2; ++mt)
#pragma unroll
    for (int r = 0; r < 4; ++r) part[mt][r] = 0.f;
#pragma unroll
  for (int mt = 0; mt < 2; ++mt)
#pragma unroll
    for (int nt = 0; nt < 4; ++nt)
#pragma unroll
      for (int r = 0; r < 4; ++r) {
        int nn = nq + nt * 16 + col;
        float y = acc[mt][nt][r] + bcnv[nn];
        part[mt][r] += fmaxf(y, 0.f) * wjnt[nn];
      }
#pragma unroll
  for (int mt = 0; mt < 2; ++mt)
#pragma unroll
    for (int r = 0; r < 4; ++r) {
      float s = part[mt][r];
      s += __shfl_xor(s, 1, 64); s += __shfl_xor(s, 2, 64);
      s += __shfl_xor(s, 4, 64); s += __shfl_xor(s, 8, 64);
      if (col == 0) jlds[w * 32 + mt * 16 + quad * 4 + r] = s;
    }
  __syncthreads();
  if (tid < 64) {
    int mh = tid >> 5, mi = tid & 31;
    float s = bjnt[0];
#pragma unroll
    for (int j = 0; j < 4; ++j) s += jlds[(mh * 4 + j) * 32 + mi];
    int jrow = g * 64 + tid;
    int b = jrow / 501, jr = jrow - b * 501;
    out_storent(outp, JN0 + (long)b * NJNT + jr, s, fm);
  }
}

// orientation head: one task = 16 rows (512 threads, 32 per row)
__device__ void body_ori(int tid, int chunk, int level,
                         const unsigned short* __restrict__ hf, const unsigned short* __restrict__ hb,
                         const float* __restrict__ wori, const float* __restrict__ bori,
                         void* __restrict__ outp, int fm) {
  int nl = 256 >> level, off = 512 - (512 >> level), sh = 8 - level;
  int i = chunk * 16 + (tid >> 5);
  int l32 = tid & 31;
  int rb = i >> sh, rp = i & (nl - 1);
  int row = rb * NORI + off + rp;
  u16x4 vf = *(const u16x4*)&hf[(long)row * HID + l32 * 4];
  u16x4 vb = *(const u16x4*)&hb[(long)row * HID + l32 * 4];
  float a0 = 0.f, a1 = 0.f;
#pragma unroll
  for (int r = 0; r < 4; ++r) {
    int k = l32 * 4 + r;
    float v = bf2f(vf[r]);
    a0 += v * wori[2 * k];
    a1 += v * wori[2 * k + 1];
    float u = bf2f(vb[r]);
    a0 += u * wori[2 * (128 + k)];
    a1 += u * wori[2 * (128 + k) + 1];
  }
#pragma unroll
  for (int m = 1; m < 32; m <<= 1) {
    a0 += __shfl_xor(a0, m, 64);
    a1 += __shfl_xor(a1, m, 64);
  }
  if (l32 == 0) {
    out_storent(outp, RD0 + (long)row * 2 + 0, a0 + bori[0], fm);
    out_storent(outp, RD0 + (long)row * 2 + 1, a1 + bori[1], fm);
  }
}

// LSTM chain, 6-slot x ring: fills issued 6 steps ahead; vmcnt(13) gates the
// fill pair needed 1 step out (13 = ops issued since that pair: 1 store +
// 4 iters x [2 fills + 1 store]); tolerance = 5 steps of fill latency (~4.5us)
// vs the old 3-slot ring's 2 (~1.8us) — rides out queue-congested L2/HBM.
__device__ void body_lstm(char* smem_, int tid, int bid,
                          const unsigned short* __restrict__ xpf, const unsigned short* __restrict__ xpb,
                          const unsigned short* __restrict__ whhf, const unsigned short* __restrict__ whhb,
                          const float* __restrict__ h0f, const float* __restrict__ c0f,
                          unsigned short* __restrict__ hf, unsigned short* __restrict__ hb) {
  unsigned short (*XS)[16][520] = (unsigned short (*)[16][520])smem_;            // 6 x 16640 B
  unsigned short (*HS)[16][136] = (unsigned short (*)[16][136])(smem_ + 99840);  // 8704 B
  int w = tid >> 6, lane = tid & 63, col = lane & 15, quad = lane >> 4;
  int chain = bid >> 2, bg = bid & 3;
  int level = chain >> 1, rev = chain & 1;
  int n = 256 >> level;
  int off = 512 - (512 >> level);
  int b0 = bg * 16;
  const unsigned short* xp  = rev ? xpb : xpf;
  const unsigned short* whh = rev ? whhb : whhf;
  unsigned short* hout = rev ? hb : hf;
  int hx0 = 16 * w + 4 * quad;

  short8 afr[4][4];
#pragma unroll
  for (int j = 0; j < 4; ++j) {
    int g = j * 128 + 16 * w + col;
#pragma unroll
    for (int kf = 0; kf < 4; ++kf)
      afr[j][kf] = *(const short8*)&whh[(long)g * HID + kf * 32 + quad * 8];
  }
  float c[4];
#pragma unroll
  for (int r = 0; r < 4; ++r) c[r] = c0f[rev * HID + hx0 + r];

#pragma unroll
  for (int q = 0; q < 4; ++q) {
    int cell = tid * 4 + q;
    HS[0][cell >> 7][cell & 127] = f2bf(tanh_(h0f[rev * HID + (cell & 127)]));
  }

  auto posAt = [&](int s) -> int { int sp = s < n ? s : n - 1; return off + (rev ? (n - 1 - sp) : sp); };
  auto fill = [&](int step, int slot) {
    int p = posAt(step);
    const unsigned short* g0 = xp + ((long)(b0 + 2 * w) * NORI + p) * NG + lane * 8;
    ld_lds16(g0, &XS[slot][2 * w][0]);
    ld_lds16(g0 + (long)NORI * NG, &XS[slot][2 * w + 1][0]);
  };
  f32x4 accN[4];
  {
    int p0 = posAt(0);
    const unsigned short* g0 = xp + ((long)(b0 + col) * NORI + p0) * NG;
    u16x4 x0[4];
#pragma unroll
    for (int j = 0; j < 4; ++j) x0[j] = *(const u16x4*)&g0[j * 128 + hx0];
    fill(1, 1); fill(2, 2); fill(3, 3); fill(4, 4); fill(5, 5);
#pragma unroll
    for (int j = 0; j < 4; ++j) {
      accN[j][0] = bf2f(x0[j][0]); accN[j][1] = bf2f(x0[j][1]);
      accN[j][2] = bf2f(x0[j][2]); accN[j][3] = bf2f(x0[j][3]);
    }
  }
  __syncthreads();   // drains all prologue DMAs (compiler emits vmcnt(0))

  long hbase = ((long)(b0 + col) * NORI) * HID;

  for (int s = 0; s < n; ++s) {
    int cur = s & 1, nxt = cur ^ 1;
    fill(s + 6, s % 6);          // overwrites x(s): read last iter, barrier-safe
    short8 bfr[4];
#pragma unroll
    for (int kf = 0; kf < 4; ++kf) bfr[kf] = *(const short8*)&HS[cur][col][kf * 32 + quad * 8];
    f32x4 acc[4];
#pragma unroll
    for (int j = 0; j < 4; ++j) acc[j] = accN[j];
#pragma unroll
    for (int kf = 0; kf < 4; ++kf) {
#pragma unroll
      for (int j = 0; j < 4; ++j)
        acc[j] = __builtin_amdgcn_mfma_f32_16x16x32_bf16(afr[j][kf], bfr[kf], acc[j], 0, 0, 0);
    }
    u16x4 xn[4];
    {
      int sl1 = (s + 1) % 6;
#pragma unroll
      for (int j = 0; j < 4; ++j) xn[j] = *(const u16x4*)&XS[sl1][col][j * 128 + hx0];
    }
    u16x4 hq;
#pragma unroll
    for (int r = 0; r < 4; ++r) {
      float A  = e2(acc[0][r]);
      float Fv = e2(acc[1][r]);
      float G  = e2(acc[2][r]);
      float O  = e2(acc[3][r]);
      float is_ = rcp_(1.f + A);
      float fs_ = rcp_(1.f + Fv);
      float tg  = 1.f - 2.f * rcp_(1.f + G);
      float cn  = fs_ * c[r] + is_ * tg;
      c[r] = cn;
      float C2  = e2(cn * (2.f * L2E));
      float tc  = 1.f - 2.f * rcp_(1.f + C2);
      hq[r] = f2bf(rcp_(1.f + O) * tc);
    }
#pragma unroll
    for (int j = 0; j < 4; ++j) {
      accN[j][0] = bf2f(xn[j][0]); accN[j][1] = bf2f(xn[j][1]);
      accN[j][2] = bf2f(xn[j][2]); accN[j][3] = bf2f(xn[j][3]);
    }
    int p = posAt(s);
    __builtin_nontemporal_store(hq, (u16x4*)&hout[hbase + (long)p * HID + hx0]);
    *(u16x4*)&HS[nxt][col][hx0] = hq;
    asm volatile("s_waitcnt vmcnt(13) lgkmcnt(0)\ns_barrier" ::: "memory");
  }
  asm volatile("s_waitcnt vmcnt(0)" ::: "memory");  // no DMA in flight at exit
}

// ---- standalone xp level-0 (feeds LSTM level-0 immediately) ----
__launch_bounds__(512, 2)
__global__ void k_xp0(const unsigned short* __restrict__ embbf,
                      const unsigned short* __restrict__ wihf, const unsigned short* __restrict__ wihb,
                      const float* __restrict__ bfp, const float* __restrict__ bbp,
                      unsigned short* __restrict__ xpf, unsigned short* __restrict__ xpb) {
  __shared__ __align__(16) char smem_[20480];
  body_xp(smem_, threadIdx.x, blockIdx.x * 2, 0, embbf, wihf, wihb, bfp, bbp, xpf, xpb);
}

// 2x-coarsened gate counts
__device__ __forceinline__ int cmbCnt(int l) { return (128 >> l) * 2; }
__device__ __forceinline__ int xpCnt(int l)  { return (256 >> l) * 4; }

// segment tables: type 0=cmb(4 tiles/task), 1=xp(4 tiles/task), 2=jnt, 3=ori, 4=lstm
__device__ const unsigned short g_segN[30] = {256,512,8, 128,256,8, 64,128,8, 32,64,8,
                                              16,32,8, 8,16,8, 4,8,8, 501,
                                              8,16,32,64,128,256,512,1024};
__device__ const unsigned char g_segT[30] = {0,1,4, 0,1,4, 0,1,4, 0,1,4, 0,1,4, 0,1,4, 0,1,4, 2,
                                             3,3,3,3,3,3,3,3};
__device__ const unsigned char g_segL[30] = {0,1,1, 1,2,2, 2,3,3, 3,4,4, 4,5,5, 5,6,6, 6,7,7, 0,
                                             7,6,5,4,3,2,1,0};

// ---- persistent mega kernel ----
// blocks 0-7: LSTM level-0 chains (zero waits -> cannot deadlock).
// blocks 8+: ticketed task queue; deps point to strictly-earlier tickets.
// Gate-acquire caching: one buffer_inv per segment per block, not per task.
__launch_bounds__(512, 1)
__global__ void k_mega(unsigned short* __restrict__ xpf, unsigned short* __restrict__ xpb,
                       const unsigned short* __restrict__ whhf, const unsigned short* __restrict__ whhb,
                       const float* __restrict__ h0f, const float* __restrict__ c0f,
                       unsigned short* __restrict__ hf, unsigned short* __restrict__ hb,
                       unsigned short* __restrict__ embbf,
                       const unsigned short* __restrict__ wihf, const unsigned short* __restrict__ wihb,
                       const float* __restrict__ bfp, const float* __restrict__ bbp,
                       const unsigned short* __restrict__ wcmbT,
                       const unsigned short* __restrict__ wc0T, const unsigned short* __restrict__ wc1T,
                       const float* __restrict__ bcmb, const float* __restrict__ bcnv,
                       const float* __restrict__ wjnt, const float* __restrict__ bjnt,
                       const float* __restrict__ wori, const float* __restrict__ bori,
                       const int* __restrict__ lhsA, const int* __restrict__ rhsA,
                       const int* __restrict__ jntA,
                       void* __restrict__ outp, const int* __restrict__ flag,
                       int* __restrict__ sync) {
  __shared__ __align__(16) char smem_[108544];   // >64KB static LDS: proven on this toolchain (r1: 118KB)
  __shared__ int s_task;
  int tid = threadIdx.x;
  int bid = blockIdx.x;

  if (bid < 8) {                      // dedicated LSTM level-0; no waits at all
    body_lstm(smem_, tid, bid, xpf, xpb, whhf, whhb, h0f, c0f, hf, hb);
    __syncthreads();
    if (tid == 0) release_add(syncp(sync, SY_H + 0));
    return;
  }

  int fm = *flag;
  int gseg = -1, gjcmb = -1;
  for (;;) {
    __syncthreads();
    if (tid == 0)
      s_task = (int)__hip_atomic_fetch_add(syncp(sync, SY_TICKET), 1,
                                           __ATOMIC_RELAXED, __HIP_MEMORY_SCOPE_AGENT);
    __syncthreads();
    int t = s_task;
    if (t >= NTASK) return;
    int seg = 0;
    while (t >= g_segN[seg]) { t -= g_segN[seg]; ++seg; }
    int typ = g_segT[seg], lv = g_segL[seg];

    if (typ == 0) {                       // combine level lv, 4 tiles
      if (lv > 0 && seg != gseg) acquire_wait(syncp(sync, SY_CMB + lv - 1), cmbCnt(lv - 1));
      gseg = seg;
      body_cmb(smem_, tid, t * 4, lv, embbf, wcmbT, bcmb, lhsA, rhsA, jntA, outp, embbf, fm);
      body_cmb(smem_, tid, t * 4 + 2, lv, embbf, wcmbT, bcmb, lhsA, rhsA, jntA, outp, embbf, fm);
      __syncthreads();
      if (tid == 0) release_add(syncp(sync, SY_CMB + lv));
    } else if (typ == 1) {                // xp level lv (lv >= 1), 4 tiles
      if (seg != gseg) acquire_wait(syncp(sync, SY_CMB + lv - 1), cmbCnt(lv - 1));
      gseg = seg;
      body_xp(smem_, tid, t * 4, lv, embbf, wihf, wihb, bfp, bbp, xpf, xpb);
      body_xp(smem_, tid, t * 4 + 2, lv, embbf, wihf, wihb, bfp, bbp, xpf, xpb);
      __syncthreads();
      if (tid == 0) release_add(syncp(sync, SY_XP + lv));
    } else if (typ == 4) {                // LSTM chain, level lv (lv >= 1)
      if (seg != gseg) acquire_wait(syncp(sync, SY_XP + lv), xpCnt(lv));
      gseg = seg;
      body_lstm(smem_, tid, 8 * lv + t, xpf, xpb, whhf, whhb, h0f, c0f, hf, hb);
      __syncthreads();
      if (tid == 0) release_add(syncp(sync, SY_H + lv));
    } else if (typ == 2) {                // joint group t
      int lmax;
      {
        int jf = t * 64, jl = t * 64 + 63;
        int bf_ = jf / 501, bl_ = jl / 501;
        int jr = (bf_ == bl_) ? (jl - bl_ * 501) : 500;
        const int joffs[8] = {0, 255, 382, 445, 476, 491, 498, 501};
        int l = 0;
        while (l < 6 && jr >= joffs[l + 1]) ++l;
        lmax = l;
      }
      if (lmax - 1 > gjcmb) {             // cmb levels complete in order -> monotone cache
        acquire_wait(syncp(sync, SY_CMB + lmax - 1), cmbCnt(lmax - 1));
        gjcmb = lmax - 1;
      }
      body_jnt(smem_, tid, t, embbf, wc0T, wc1T, bcnv, wjnt, bjnt, outp, fm);
    } else {                              // ori level lv, chunk t
      if (seg != gseg) acquire_wait(syncp(sync, SY_H + lv), 8);
      gseg = seg;
      body_ori(tid, t, lv, hf, hb, wori, bori, outp, fm);
    }
  }
}

extern "C" void kernel_launch(void* const* d_in, const int* in_sizes, int n_in,
                              void* d_out, int out_size, void* d_ws, size_t ws_size,
                              hipStream_t stream) {
  (void)in_sizes; (void)n_in; (void)out_size;
  const void* unit_emb  = d_in[0];
  const void* existence = d_in[1];
  const void* sright    = d_in[2];
  const void* sjoint    = d_in[3];
  const void* h0        = d_in[4];
  const void* c0        = d_in[5];
  const void* wih_f     = d_in[6];
  const void* whh_f     = d_in[7];
  const void* b_f       = d_in[8];
  const void* wih_b     = d_in[9];
  const void* whh_b     = d_in[10];
  const void* b_b       = d_in[11];
  const void* w_ori     = d_in[12];
  const void* b_ori     = d_in[13];
  const void* w_cnv     = d_in[14];
  const void* b_cnv     = d_in[15];
  const void* w_jnt     = d_in[16];
  const void* b_jnt     = d_in[17];
  const void* w_cmb     = d_in[18];
  const void* b_cmb     = d_in[19];

  char* wsb = (char*)d_ws;
  size_t off = 0;
  auto alloc = [&](size_t bytes) -> void* {
    void* r = wsb + off;
    off += (bytes + 255) & ~(size_t)255;
    return r;
  };
  int* flag = (int*)alloc(sizeof(int));
  int* sync = (int*)alloc(4096 * sizeof(int));   // 64 counters x 256B padding
  unsigned short* embbf = (unsigned short*)alloc((size_t)B * NORI * DM * 2);
  unsigned short* xpf   = (unsigned short*)alloc((size_t)B * NORI * NG * 2);
  unsigned short* xpb   = (unsigned short*)alloc((size_t)B * NORI * NG * 2);
  unsigned short* hfb   = (unsigned short*)alloc((size_t)B * NORI * HID * 2);
  unsigned short* hbb   = (unsigned short*)alloc((size_t)B * NORI * HID * 2);
  unsigned short* wihf  = (unsigned short*)alloc(512 * 512 * 2);
  unsigned short* wihb  = (unsigned short*)alloc(512 * 512 * 2);
  unsigned short* whhfb = (unsigned short*)alloc(512 * 128 * 2);
  unsigned short* whhbb = (unsigned short*)alloc(512 * 128 * 2);
  unsigned short* wcmbT = (unsigned short*)alloc(512 * 1024 * 2);
  unsigned short* wc0T  = (unsigned short*)alloc(256 * 512 * 2);
  unsigned short* wc1T  = (unsigned short*)alloc(256 * 512 * 2);
  float* bf32   = (float*)alloc(512 * 4);
  float* bb32   = (float*)alloc(512 * 4);
  float* bcnv32 = (float*)alloc(256 * 4);
  float* bori32 = (float*)alloc(2 * 4);
  float* bjnt32 = (float*)alloc(1 * 4);
  float* bcmb32 = (float*)alloc(512 * 4);
  float* wori32 = (float*)alloc(512 * 4);
  float* wjnt32 = (float*)alloc(256 * 4);
  float* h0f    = (float*)alloc(256 * 4);
  float* c0f    = (float*)alloc(256 * 4);
  int* lhsA = (int*)alloc((size_t)7 * B * 128 * 4);
  int* rhsA = (int*)alloc((size_t)7 * B * 128 * 4);
  int* jntA = (int*)alloc((size_t)7 * B * 128 * 4);
  if (off > ws_size) return;

  k_detect<<<1, 256, 0, stream>>>((const unsigned int*)unit_emb, flag);
  k_prep_all<<<38990, 256, 0, stream>>>(unit_emb, sright, sjoint, existence,
                                        wih_f, wih_b, whh_f, whh_b, w_cmb, w_cnv,
                                        b_f, b_b, b_cnv, b_ori, b_jnt, b_cmb, w_ori, w_jnt, h0, c0,
                                        wihf, wihb, whhfb, whhbb, wcmbT, wc0T, wc1T,
                                        bf32, bb32, bcnv32, bori32, bjnt32, bcmb32, wori32, wjnt32,
                                        h0f, c0f, d_out, embbf, lhsA, rhsA, jntA, flag, sync);
  k_xp0<<<2048, 512, 0, stream>>>(embbf, wihf, wihb, bf32, bb32, xpf, xpb);
  k_mega<<<256, 512, 0, stream>>>(xpf, xpb, whhfb, whhbb, h0f, c0f, hfb, hbb, embbf,
                                  wihf, wihb, bf32, bb32, wcmbT, wc0T, wc1T,
                                  bcmb32, bcnv32, wjnt32, bjnt32, wori32, bori32,
                                  lhsA, rhsA, jntA, d_out, flag, sync);
}

// Round 8
// 651.171 us; speedup vs baseline: 1.1844x; 1.1844x over previous
//
#include <hip/hip_runtime.h>

#define B 64
#define NORI 510
#define NJNT 501
#define DM 512
#define HID 128
#define NG 512

constexpr long EMB0 = (long)B * NORI;                    // existence size
constexpr long RD0  = EMB0 + (long)B * NORI * DM;        // right_direc offset
constexpr long JN0  = RD0 + (long)B * NORI * 2;          // joint offset

// sync[] counters, each padded to its own 256B line (64 ints apart).
#define SY_TICKET 0
#define SY_CMB 1    // +l, l=0..6 : combine-level-l finished tasks
#define SY_XP  8    // +l, l=1..7 : xp-level-l finished tasks
#define SY_H   16   // +l, l=0..7 : LSTM chains finished (8 per level)
#define NTASK 4121
__device__ __forceinline__ int* syncp(int* s, int idx) { return s + idx * 64; }

typedef __attribute__((ext_vector_type(8))) short short8;
typedef __attribute__((ext_vector_type(4))) float f32x4;
typedef __attribute__((ext_vector_type(4))) unsigned short u16x4;
typedef __attribute__((ext_vector_type(4))) unsigned int u32x4;

__device__ __forceinline__ float bf2f(unsigned short u) {
  unsigned int x = ((unsigned int)u) << 16;
  return __builtin_bit_cast(float, x);
}
__device__ __forceinline__ unsigned short f2bf(float f) {
  unsigned int x = __builtin_bit_cast(unsigned int, f);
  unsigned int r = (x + 0x7FFFu + ((x >> 16) & 1u)) >> 16;
  return (unsigned short)r;
}
__device__ __forceinline__ float sigm(float x) { return 1.f / (1.f + __expf(-x)); }
__device__ __forceinline__ float tanh_(float x) { return 2.f / (1.f + __expf(-2.f * x)) - 1.f; }
__device__ __forceinline__ float e2(float x) { return __builtin_amdgcn_exp2f(x); }
__device__ __forceinline__ float rcp_(float x) { return __builtin_amdgcn_rcpf(x); }
#define L2E 1.4426950408889634f

__device__ __forceinline__ void ld_lds16(const void* g, void* l) {
  __builtin_amdgcn_global_load_lds(
      (const __attribute__((address_space(1))) unsigned int*)g,
      (__attribute__((address_space(3))) unsigned int*)l, 16, 0, 0);
}

__device__ __forceinline__ float in_load(const void* p, long i, int fm) {
  return fm ? bf2f(((const unsigned short*)p)[i]) : ((const float*)p)[i];
}
__device__ __forceinline__ float out_loadf(const void* p, long i, int fm) {
  return fm ? bf2f(((const unsigned short*)p)[i]) : ((const float*)p)[i];
}
__device__ __forceinline__ void out_storef(void* p, long i, float v, int fm) {
  if (fm) ((unsigned short*)p)[i] = f2bf(v);
  else    ((float*)p)[i] = v;
}
// non-temporal: ONLY for write-only outputs (joint, right_direc). r7 lesson:
// NT on consumed buffers (xp/emb/h) evicts them from L2 -> consumers hit HBM.
__device__ __forceinline__ void out_storent(void* p, long i, float v, int fm) {
  if (fm) __builtin_nontemporal_store(f2bf(v), (unsigned short*)p + i);
  else    __builtin_nontemporal_store(v, (float*)p + i);
}
__device__ __forceinline__ unsigned short cvbf(const void* p, long i, int fm) {
  return fm ? ((const unsigned short*)p)[i] : f2bf(((const float*)p)[i]);
}

// gate scale: gates i,f,o pre-scaled by -log2(e); gate g by +2*log2(e).
__device__ __forceinline__ float gsc(int gate) {
  return (gate == 2) ? (2.f * L2E) : (-L2E);
}

__device__ __forceinline__ int bmode(const void* p) {
  unsigned int u = *(const unsigned int*)p;
  if (u == 1u) return 1;
  if (u == 0x3F800000u) return 2;
  if (u == 0x00003F80u || u == 0x3F803F80u) return 3;
  return 0;
}
__device__ __forceinline__ bool loadb(const void* p, long i, int m) {
  switch (m) {
    case 1: return ((const int*)p)[i] != 0;
    case 2: return ((const float*)p)[i] != 0.f;
    case 3: return ((const unsigned short*)p)[i] != 0;
    default: return ((const unsigned char*)p)[i] != 0;
  }
}

// ---- device-scope flag sync (r5-verified): ONE relaxed spinner per block,
// one ACQUIRE on success, ~20ms watchdog.
__device__ __forceinline__ void acquire_wait(int* f, int target) {
  if (threadIdx.x == 0) {
    unsigned long t0 = __builtin_amdgcn_s_memrealtime();
    while (__hip_atomic_load(f, __ATOMIC_RELAXED, __HIP_MEMORY_SCOPE_AGENT) < target) {
      __builtin_amdgcn_s_sleep(8);
      if (__builtin_amdgcn_s_memrealtime() - t0 > 2000000UL) break;
    }
    (void)__hip_atomic_load(f, __ATOMIC_ACQUIRE, __HIP_MEMORY_SCOPE_AGENT);
  }
  __syncthreads();
}
__device__ __forceinline__ void release_add(int* f) {
  __hip_atomic_fetch_add(f, 1, __ATOMIC_RELEASE, __HIP_MEMORY_SCOPE_AGENT);
}

// ---- detect f32 vs bf16 float inputs ----
__global__ void k_detect(const unsigned int* raw, int* flag) {
  __shared__ int cnt[256];
  int t = threadIdx.x;
  unsigned int u = raw[(long)t * 16001];
  unsigned int e = (u >> 8) & 0x7F;
  cnt[t] = (e >= 0x34 && e <= 0x44) ? 1 : 0;
  __syncthreads();
  for (int d = 128; d; d >>= 1) { if (t < d) cnt[t] += cnt[t + d]; __syncthreads(); }
  if (t == 0) flag[0] = (cnt[0] >= 128) ? 1 : 0;
}

// ---- ALL prep work in one launch + sync-flag zeroing ----
__global__ void k_prep_all(const void* ue, const void* sright, const void* sjoint, const void* exist,
                           const void* wih_f, const void* wih_b, const void* whh_f, const void* whh_b,
                           const void* w_cmb, const void* w_cnv,
                           const void* b_f, const void* b_b, const void* b_cnv, const void* b_ori,
                           const void* b_jnt, const void* b_cmb, const void* w_ori, const void* w_jnt,
                           const void* h0, const void* c0,
                           unsigned short* d_wihf, unsigned short* d_wihb,
                           unsigned short* d_whhf, unsigned short* d_whhb,
                           unsigned short* wcmbT, unsigned short* wc0T, unsigned short* wc1T,
                           float* d_bf, float* d_bb, float* d_bcnv, float* d_bori, float* d_bjnt,
                           float* d_bcmb, float* d_wori, float* d_wjnt, float* d_h0, float* d_c0,
                           void* outp, unsigned short* embw,
                           int* lhsA, int* rhsA, int* jntA,
                           const int* flag, int* sync) {
  __shared__ int sc[256];
  int fm = *flag;
  int bx = blockIdx.x, t = threadIdx.x;
  if (bx < 2560) {                       // wih/whh -> bf16, pre-scaled per gate
    int i = bx * 256 + t;
    if (i < 262144) {
      int row = i >> 9;
      d_wihf[i] = f2bf(in_load(wih_f, i, fm) * gsc(row >> 7));
    } else if (i < 524288) {
      int k = i - 262144; int row = k >> 9;
      d_wihb[k] = f2bf(in_load(wih_b, k, fm) * gsc(row >> 7));
    } else if (i < 589824) {
      int k = i - 524288; int row = k >> 7;
      d_whhf[k] = f2bf(in_load(whh_f, k, fm) * gsc(row >> 7));
    } else if (i < 655360) {
      int k = i - 589824; int row = k >> 7;
      d_whhb[k] = f2bf(in_load(whh_b, k, fm) * gsc(row >> 7));
    }
  } else if (bx < 4608) {                // w_cmb^T (1024x512)
    int i = (bx - 2560) * 256 + t;
    int r = i / 512, c = i - r * 512;
    wcmbT[(long)c * 1024 + r] = f2bf(in_load(w_cmb, i, fm));
  } else if (bx < 5120) {                // w_cnv[0]^T (512x256)
    int i = (bx - 4608) * 256 + t;
    int r = i / 256, c = i - r * 256;
    wc0T[(long)c * 512 + r] = f2bf(in_load(w_cnv, i, fm));
  } else if (bx < 5632) {                // w_cnv[1]^T
    int i = (bx - 5120) * 256 + t;
    int r = i / 256, c = i - r * 256;
    wc1T[(long)c * 512 + r] = f2bf(in_load(w_cnv, (long)512 * 256 + i, fm));
  } else if (bx < 5645) {                // small f32 params (b_f/b_b gate-scaled)
    int i = (bx - 5632) * 256 + t;
    if (i < 512)       d_bf[i] = in_load(b_f, i, fm) * gsc(i >> 7);
    else if (i < 1024) { int k = i - 512; d_bb[k] = in_load(b_b, k, fm) * gsc(k >> 7); }
    else if (i < 1280) d_bcnv[i - 1024] = in_load(b_cnv, i - 1024, fm);
    else if (i < 1282) d_bori[i - 1280] = in_load(b_ori, i - 1280, fm);
    else if (i < 1283) d_bjnt[i - 1282] = in_load(b_jnt, i - 1282, fm);
    else if (i < 1795) d_bcmb[i - 1283] = in_load(b_cmb, i - 1283, fm);
    else if (i < 2307) d_wori[i - 1795] = in_load(w_ori, i - 1795, fm);
    else if (i < 2563) d_wjnt[i - 2307] = in_load(w_jnt, i - 2307, fm);
    else if (i < 2819) d_h0[i - 2563] = in_load(h0, i - 2563, fm);
    else if (i < 3075) d_c0[i - 2819] = in_load(c0, i - 2819, fm);
  } else if (bx < 5773) {                // existence_out = 1
    int i = (bx - 5645) * 256 + t;
    if (i < B * NORI) out_storef(outp, i, 1.0f, fm);
  } else if (bx < 38541) {               // emb level-0 init
    long i = (long)(bx - 5773) * 256 + t;
    int bb = (int)(i >> 17);
    int p  = (int)((i >> 9) & 255);
    int d  = (int)(i & 511);
    float v = in_load(ue, i, fm);
    long row = (long)(bb * NORI + p) * DM + d;
    out_storef(outp, EMB0 + row, v, fm);
    embw[row] = f2bf(v);
  } else if (bx < 38989) {               // split/merge, all 7 levels
    int idx = bx - 38541;
    int level = idx >> 6, b = idx & 63;
    int n = 256 >> level, n2 = n >> 1;
    int offr = 512 - (512 >> level);
    int offj = offr - level;
    int mr = bmode(sright), mj = bmode(sjoint), me = bmode(exist);
    int* lhs = lhsA + level * B * 128;
    int* rhs = rhsA + level * B * 128;
    int* jnt = jntA + level * B * 128;
    int i = t;
    bool pj = false, ns = false;
    if (i < n) {
      bool ri   = loadb(sright, (long)b * NORI + offr + i, mr);
      bool rim1 = (i > 0)     ? loadb(sright, (long)b * NORI + offr + i - 1, mr) : false;
      bool rip1 = (i + 1 < n) ? loadb(sright, (long)b * NORI + offr + i + 1, mr) : false;
      bool ji   = (i < n - 1) ? loadb(sjoint, (long)b * NJNT + offj + i, mj) : false;
      bool jim1 = (i > 0)     ? loadb(sjoint, (long)b * NJNT + offj + i - 1, mj) : false;
      pj = (i < n - 1) && ri && !rip1 && ji;
      bool rhs_is = (i > 0) && rim1 && !ri && jim1;
      bool ex = (level == 0) ? loadb(exist, (long)b * 256 + i, me) : true;
      ns = ex && !rhs_is;
    }
    sc[i] = (i < n && ns) ? 1 : 0;
    if (i < n2) { lhs[b * n2 + i] = 0; rhs[b * n2 + i] = 0; jnt[b * n2 + i] = 0; }
    __syncthreads();
    for (int d = 1; d < 256; d <<= 1) {
      int v = sc[i];
      int u = (i >= d) ? sc[i - d] : 0;
      __syncthreads();
      sc[i] = v + u;
      __syncthreads();
    }
    if (i < n) {
      int nid = sc[i] - 1;
      if (ns && nid >= 0 && nid < n2) lhs[b * n2 + nid] = i;
      if (pj && nid >= 0 && nid < n2) { rhs[b * n2 + nid] = i + 1; jnt[b * n2 + nid] = 1; }
    }
  } else {                               // zero padded sync counters (4096 ints)
    for (int i = t; i < 4096; i += 256) sync[i] = 0;
  }
}

// ================= task bodies =================
// r8: K-step 64 (8-16 MFMA per barrier pair, half the barriers) — the queue
// was barrier-paced at ~5% MfmaUtil with K-step 32.

// xp GEMM: 2 x 64x64 tiles (512 threads, 256 per subtile)
__device__ void body_xp(char* smem_, int tid, int tile0, int level,
                        const unsigned short* __restrict__ embbf,
                        const unsigned short* __restrict__ wihf, const unsigned short* __restrict__ wihb,
                        const float* __restrict__ bfp, const float* __restrict__ bbp,
                        unsigned short* __restrict__ xpf, unsigned short* __restrict__ xpb) {
  int sub = tid >> 8, t5 = tid & 255;
  int tile = tile0 + sub;
  unsigned short (*As)[72] = (unsigned short (*)[72])(smem_ + sub * 18432);
  unsigned short (*Bs)[72] = (unsigned short (*)[72])(smem_ + sub * 18432 + 9216);
  int nb = tile & 15, mb = tile >> 4;
  const unsigned short* Bt = (nb < 8) ? wihf : wihb;
  const float* bias = (nb < 8) ? bfp : bbp;
  unsigned short* out = (nb < 8) ? xpf : xpb;
  int m0 = mb * 64, n0 = (nb & 7) * 64;
  int nl = 256 >> level, off = 512 - (512 >> level), sh = 8 - level;
  int lane = t5 & 63, wv = t5 >> 6;
  int col = lane & 15, quad = lane >> 4;
  int mq = (wv >> 1) * 32, nq = (wv & 1) * 32;
  int sr = t5 >> 2, sc = (t5 & 3) * 16;
  int mi = m0 + sr;
  int rb = mi >> sh, rp = mi & (nl - 1);
  const unsigned short* ap = &embbf[((long)(rb * NORI + off + rp)) * DM + sc];
  const unsigned short* bp = &Bt[(long)(n0 + sr) * DM + sc];
  f32x4 zero = {0.f, 0.f, 0.f, 0.f};
  f32x4 acc[2][2];
  acc[0][0] = zero; acc[0][1] = zero; acc[1][0] = zero; acc[1][1] = zero;
  u32x4 av0 = *(const u32x4*)(ap), av1 = *(const u32x4*)(ap + 8);
  u32x4 bv0 = *(const u32x4*)(bp), bv1 = *(const u32x4*)(bp + 8);
  for (int k0 = 0; k0 < DM; k0 += 64) {
    __syncthreads();
    *(u32x4*)&As[sr][sc] = av0; *(u32x4*)&As[sr][sc + 8] = av1;
    *(u32x4*)&Bs[sr][sc] = bv0; *(u32x4*)&Bs[sr][sc + 8] = bv1;
    __syncthreads();
    if (k0 + 64 < DM) {
      av0 = *(const u32x4*)(ap + k0 + 64); av1 = *(const u32x4*)(ap + k0 + 72);
      bv0 = *(const u32x4*)(bp + k0 + 64); bv1 = *(const u32x4*)(bp + k0 + 72);
    }
#pragma unroll
    for (int kf = 0; kf < 2; ++kf) {
      short8 a0 = *(const short8*)&As[mq + col][kf * 32 + quad * 8];
      short8 a1 = *(const short8*)&As[mq + 16 + col][kf * 32 + quad * 8];
      short8 b0 = *(const short8*)&Bs[nq + col][kf * 32 + quad * 8];
      short8 b1 = *(const short8*)&Bs[nq + 16 + col][kf * 32 + quad * 8];
      acc[0][0] = __builtin_amdgcn_mfma_f32_16x16x32_bf16(a0, b0, acc[0][0], 0, 0, 0);
      acc[0][1] = __builtin_amdgcn_mfma_f32_16x16x32_bf16(a0, b1, acc[0][1], 0, 0, 0);
      acc[1][0] = __builtin_amdgcn_mfma_f32_16x16x32_bf16(a1, b0, acc[1][0], 0, 0, 0);
      acc[1][1] = __builtin_amdgcn_mfma_f32_16x16x32_bf16(a1, b1, acc[1][1], 0, 0, 0);
    }
  }
#pragma unroll
  for (int mt = 0; mt < 2; ++mt)
#pragma unroll
    for (int nt = 0; nt < 2; ++nt)
#pragma unroll
      for (int r = 0; r < 4; ++r) {
        int m = m0 + mq + mt * 16 + quad * 4 + r;
        int ob = m >> sh, op = m & (nl - 1);
        int n = n0 + nq + nt * 16 + col;
        out[((long)(ob * NORI + off + op)) * NG + n] = f2bf(acc[mt][nt][r] + bias[n]);
      }
}

// combine GEMM + gated merge: 2 x 64x64 tiles
__device__ void body_cmb(char* smem_, int tid, int tile0, int level,
                         const unsigned short* __restrict__ embbf,
                         const unsigned short* __restrict__ wcmbT,
                         const float* __restrict__ bcmb,
                         const int* __restrict__ lhsA, const int* __restrict__ rhsA,
                         const int* __restrict__ jntA,
                         void* __restrict__ outp, unsigned short* __restrict__ embw, int fm) {
  int n2 = 128 >> level, lg = 7 - level;
  int off = 512 - (512 >> level);
  int off2 = 512 - (256 >> level);
  const int* lhs = lhsA + level * B * 128;
  const int* rhs = rhsA + level * B * 128;
  const int* jntf = jntA + level * B * 128;
  int sub = tid >> 8, t5 = tid & 255;
  int tile = tile0 + sub;
  unsigned short (*As)[72] = (unsigned short (*)[72])(smem_ + sub * 18432);
  unsigned short (*Bs)[72] = (unsigned short (*)[72])(smem_ + sub * 18432 + 9216);
  int nb = tile & 7, mb = tile >> 3;
  int m0 = mb * 64, n0 = nb * 64;
  int lane = t5 & 63, wv = t5 >> 6;
  int col = lane & 15, quad = lane >> 4;
  int mq = (wv >> 1) * 32, nq = (wv & 1) * 32;
  int sr = t5 >> 2, sc = (t5 & 3) * 16;
  int rm = m0 + sr;
  int rb = rm >> lg, rj = rm & (n2 - 1);
  int li = lhs[rb * n2 + rj], ri = rhs[rb * n2 + rj];
  long arowL = ((long)(rb * NORI + off + li)) * DM;
  long arowR = ((long)(rb * NORI + off + ri)) * DM;
  const unsigned short* bp = &wcmbT[(long)(n0 + sr) * 1024 + sc];
  f32x4 zero = {0.f, 0.f, 0.f, 0.f};
  f32x4 acc[2][2];
  acc[0][0] = zero; acc[0][1] = zero; acc[1][0] = zero; acc[1][1] = zero;
  u32x4 av0 = *(const u32x4*)&embbf[arowL + sc], av1 = *(const u32x4*)&embbf[arowL + sc + 8];
  u32x4 bv0 = *(const u32x4*)(bp), bv1 = *(const u32x4*)(bp + 8);
  for (int k0 = 0; k0 < 1024; k0 += 64) {
    __syncthreads();
    *(u32x4*)&As[sr][sc] = av0; *(u32x4*)&As[sr][sc + 8] = av1;
    *(u32x4*)&Bs[sr][sc] = bv0; *(u32x4*)&Bs[sr][sc + 8] = bv1;
    __syncthreads();
    int kn = k0 + 64;
    if (kn < 1024) {
      long abase = (kn < 512) ? arowL : arowR;
      int kk = (kn & 511) + sc;
      av0 = *(const u32x4*)&embbf[abase + kk]; av1 = *(const u32x4*)&embbf[abase + kk + 8];
      bv0 = *(const u32x4*)(bp + kn); bv1 = *(const u32x4*)(bp + kn + 8);
    }
#pragma unroll
    for (int kf = 0; kf < 2; ++kf) {
      short8 a0 = *(const short8*)&As[mq + col][kf * 32 + quad * 8];
      short8 a1 = *(const short8*)&As[mq + 16 + col][kf * 32 + quad * 8];
      short8 b0 = *(const short8*)&Bs[nq + col][kf * 32 + quad * 8];
      short8 b1 = *(const short8*)&Bs[nq + 16 + col][kf * 32 + quad * 8];
      acc[0][0] = __builtin_amdgcn_mfma_f32_16x16x32_bf16(a0, b0, acc[0][0], 0, 0, 0);
      acc[0][1] = __builtin_amdgcn_mfma_f32_16x16x32_bf16(a0, b1, acc[0][1], 0, 0, 0);
      acc[1][0] = __builtin_amdgcn_mfma_f32_16x16x32_bf16(a1, b0, acc[1][0], 0, 0, 0);
      acc[1][1] = __builtin_amdgcn_mfma_f32_16x16x32_bf16(a1, b1, acc[1][1], 0, 0, 0);
    }
  }
#pragma unroll
  for (int mt = 0; mt < 2; ++mt) {
#pragma unroll
    for (int r = 0; r < 4; ++r) {
      int mm = m0 + mq + mt * 16 + quad * 4 + r;
      int eb = mm >> lg, ej = mm & (n2 - 1);
      int eli = lhs[eb * n2 + ej];
      int eji = jntf[eb * n2 + ej];
      int eri = rhs[eb * n2 + ej];
#pragma unroll
      for (int nt = 0; nt < 2; ++nt) {
        int nn = n0 + nq + nt * 16 + col;
        float g = sigm(acc[mt][nt][r] + bcmb[nn]);
        float lv = out_loadf(outp, EMB0 + ((long)(eb * NORI + off + eli)) * DM + nn, fm);
        float res;
        if (eji) {
          float rv = out_loadf(outp, EMB0 + ((long)(eb * NORI + off + eri)) * DM + nn, fm);
          res = g * lv + (1.f - g) * rv;
        } else res = lv;
        long didx = ((long)(eb * NORI + off2 + ej)) * DM + nn;
        out_storef(outp, EMB0 + didx, res, fm);
        embw[didx] = f2bf(res);
      }
    }
  }
}

// joint head: one 64-row x 256-col group, K=1024, fused reduce (512 threads)
__device__ void body_jnt(char* smem_, int tid, int g,
                         const unsigned short* __restrict__ embbf,
                         const unsigned short* __restrict__ wc0T, const unsigned short* __restrict__ wc1T,
                         const float* __restrict__ bcnv, const float* __restrict__ wjnt,
                         const float* __restrict__ bjnt, void* __restrict__ outp, int fm) {
  unsigned short (*As)[72] = (unsigned short (*)[72])smem_;               // 64 rows, 9216 B
  unsigned short (*Bs)[72] = (unsigned short (*)[72])(smem_ + 9216);      // 256 rows, 36864 B
  float* jlds = (float*)(smem_ + 9216 + 36864);
  const int joffs[8] = {0, 255, 382, 445, 476, 491, 498, 501};
  int w = tid >> 6, lane = tid & 63, col = lane & 15, quad = lane >> 4;
  int mq = (w >> 2) * 32, nq = (w & 3) * 64;
  int sc = (tid & 3) * 16;

  const unsigned short* aptr = embbf;
  if (tid < 256) {
    int jrow = g * 64 + (tid >> 2);
    int b = jrow / 501, jr = jrow - b * 501;
    int l = 0;
    while (l < 6 && jr >= joffs[l + 1]) ++l;
    int t_ = jr - joffs[l];
    int offl = 512 - (512 >> l);
    aptr = embbf + ((long)(b * NORI + offl + t_)) * DM;
  }
  int brow1 = tid >> 2, brow2 = brow1 + 128;

  f32x4 zero = {0.f, 0.f, 0.f, 0.f};
  f32x4 acc[2][4];
#pragma unroll
  for (int mt = 0; mt < 2; ++mt)
#pragma unroll
    for (int nt = 0; nt < 4; ++nt) acc[mt][nt] = zero;

  u32x4 av0, av1, bv10, bv11, bv20, bv21;
  if (tid < 256) { av0 = *(const u32x4*)(aptr + sc); av1 = *(const u32x4*)(aptr + sc + 8); }
  bv10 = *(const u32x4*)&wc0T[(long)brow1 * DM + sc];
  bv11 = *(const u32x4*)&wc0T[(long)brow1 * DM + sc + 8];
  bv20 = *(const u32x4*)&wc0T[(long)brow2 * DM + sc];
  bv21 = *(const u32x4*)&wc0T[(long)brow2 * DM + sc + 8];
  for (int kk = 0; kk < 1024; kk += 64) {
    __syncthreads();
    if (tid < 256) { *(u32x4*)&As[tid >> 2][sc] = av0; *(u32x4*)&As[tid >> 2][sc + 8] = av1; }
    *(u32x4*)&Bs[brow1][sc] = bv10; *(u32x4*)&Bs[brow1][sc + 8] = bv11;
    *(u32x4*)&Bs[brow2][sc] = bv20; *(u32x4*)&Bs[brow2][sc + 8] = bv21;
    __syncthreads();
    int kn = kk + 64;
    if (kn < 1024) {
      const unsigned short* Bn = (kn >> 9) ? wc1T : wc0T;
      int kb = (kn & 511) + sc;
      if (tid < 256) { av0 = *(const u32x4*)(aptr + kn + sc); av1 = *(const u32x4*)(aptr + kn + sc + 8); }
      bv10 = *(const u32x4*)&Bn[(long)brow1 * DM + kb];
      bv11 = *(const u32x4*)&Bn[(long)brow1 * DM + kb + 8];
      bv20 = *(const u32x4*)&Bn[(long)brow2 * DM + kb];
      bv21 = *(const u32x4*)&Bn[(long)brow2 * DM + kb + 8];
    }
#pragma unroll
    for (int kf = 0; kf < 2; ++kf) {
      short8 a0 = *(const short8*)&As[mq + col][kf * 32 + quad * 8];
      short8 a1 = *(const short8*)&As[mq + 16 + col][kf * 32 + quad * 8];
#pragma unroll
      for (int nt = 0; nt < 4; ++nt) {
        short8 bfr = *(const short8*)&Bs[nq + nt * 16 + col][kf * 32 + quad * 8];
        acc[0][nt] = __builtin_amdgcn_mfma_f32_16x16x32_bf16(a0, bfr, acc[0][nt], 0, 0, 0);
        acc[1][nt] = __builtin_amdgcn_mfma_f32_16x16x32_bf16(a1, bfr, acc[1][nt], 0, 0, 0);
      }
    }
  }
  float part[2][4];
#pragma unroll
  for (int mt = 0; mt < 2; ++mt)
#pragma unroll
    for (int r = 0; r < 4; ++r) part[mt][r] = 0.f;
#pragma unroll
  for (int mt = 0; mt < 2; ++mt)
#pragma unroll
    for (int nt = 0; nt < 4; ++nt)
#pragma unroll
      for (int r = 0; r < 4; ++r) {
        int nn = nq + nt * 16 + col;
        float y = acc[mt][nt][r] + bcnv[nn];
        part[mt][r] += fmaxf(y, 0.f) * wjnt[nn];
      }
#pragma unroll
  for (int mt = 0; mt < 2; ++mt)
#pragma unroll
    for (int r = 0; r < 4; ++r) {
      float s = part[mt][r];
      s += __shfl_xor(s, 1, 64); s += __shfl_xor(s, 2, 64);
      s += __shfl_xor(s, 4, 64); s += __shfl_xor(s, 8, 64);
      if (col == 0) jlds[w * 32 + mt * 16 + quad * 4 + r] = s;
    }
  __syncthreads();
  if (tid < 64) {
    int mh = tid >> 5, mi = tid & 31;
    float s = bjnt[0];
#pragma unroll
    for (int j = 0; j < 4; ++j) s += jlds[(mh * 4 + j) * 32 + mi];
    int jrow = g * 64 + tid;
    int b = jrow / 501, jr = jrow - b * 501;
    out_storent(outp, JN0 + (long)b * NJNT + jr, s, fm);   // write-only output
  }
}

// orientation head: one task = 16 rows (512 threads, 32 per row)
__device__ void body_ori(int tid, int chunk, int level,
                         const unsigned short* __restrict__ hf, const unsigned short* __restrict__ hb,
                         const float* __restrict__ wori, const float* __restrict__ bori,
                         void* __restrict__ outp, int fm) {
  int nl = 256 >> level, off = 512 - (512 >> level), sh = 8 - level;
  int i = chunk * 16 + (tid >> 5);
  int l32 = tid & 31;
  int rb = i >> sh, rp = i & (nl - 1);
  int row = rb * NORI + off + rp;
  u16x4 vf = *(const u16x4*)&hf[(long)row * HID + l32 * 4];
  u16x4 vb = *(const u16x4*)&hb[(long)row * HID + l32 * 4];
  float a0 = 0.f, a1 = 0.f;
#pragma unroll
  for (int r = 0; r < 4; ++r) {
    int k = l32 * 4 + r;
    float v = bf2f(vf[r]);
    a0 += v * wori[2 * k];
    a1 += v * wori[2 * k + 1];
    float u = bf2f(vb[r]);
    a0 += u * wori[2 * (128 + k)];
    a1 += u * wori[2 * (128 + k) + 1];
  }
#pragma unroll
  for (int m = 1; m < 32; m <<= 1) {
    a0 += __shfl_xor(a0, m, 64);
    a1 += __shfl_xor(a1, m, 64);
  }
  if (l32 == 0) {
    out_storent(outp, RD0 + (long)row * 2 + 0, a0 + bori[0], fm);   // write-only
    out_storent(outp, RD0 + (long)row * 2 + 1, a1 + bori[1], fm);
  }
}

// LSTM chain, 6-slot x ring (r7-verified): fills 6 ahead, vmcnt(13) gates the
// x(s+1) fill pair exactly; tolerance ~5 steps of fill latency.
__device__ void body_lstm(char* smem_, int tid, int bid,
                          const unsigned short* __restrict__ xpf, const unsigned short* __restrict__ xpb,
                          const unsigned short* __restrict__ whhf, const unsigned short* __restrict__ whhb,
                          const float* __restrict__ h0f, const float* __restrict__ c0f,
                          unsigned short* __restrict__ hf, unsigned short* __restrict__ hb) {
  unsigned short (*XS)[16][520] = (unsigned short (*)[16][520])smem_;            // 6 x 16640 B
  unsigned short (*HS)[16][136] = (unsigned short (*)[16][136])(smem_ + 99840);  // 8704 B
  int w = tid >> 6, lane = tid & 63, col = lane & 15, quad = lane >> 4;
  int chain = bid >> 2, bg = bid & 3;
  int level = chain >> 1, rev = chain & 1;
  int n = 256 >> level;
  int off = 512 - (512 >> level);
  int b0 = bg * 16;
  const unsigned short* xp  = rev ? xpb : xpf;
  const unsigned short* whh = rev ? whhb : whhf;
  unsigned short* hout = rev ? hb : hf;
  int hx0 = 16 * w + 4 * quad;

  short8 afr[4][4];
#pragma unroll
  for (int j = 0; j < 4; ++j) {
    int g = j * 128 + 16 * w + col;
#pragma unroll
    for (int kf = 0; kf < 4; ++kf)
      afr[j][kf] = *(const short8*)&whh[(long)g * HID + kf * 32 + quad * 8];
  }
  float c[4];
#pragma unroll
  for (int r = 0; r < 4; ++r) c[r] = c0f[rev * HID + hx0 + r];

#pragma unroll
  for (int q = 0; q < 4; ++q) {
    int cell = tid * 4 + q;
    HS[0][cell >> 7][cell & 127] = f2bf(tanh_(h0f[rev * HID + (cell & 127)]));
  }

  auto posAt = [&](int s) -> int { int sp = s < n ? s : n - 1; return off + (rev ? (n - 1 - sp) : sp); };
  auto fill = [&](int step, int slot) {
    int p = posAt(step);
    const unsigned short* g0 = xp + ((long)(b0 + 2 * w) * NORI + p) * NG + lane * 8;
    ld_lds16(g0, &XS[slot][2 * w][0]);
    ld_lds16(g0 + (long)NORI * NG, &XS[slot][2 * w + 1][0]);
  };
  f32x4 accN[4];
  {
    int p0 = posAt(0);
    const unsigned short* g0 = xp + ((long)(b0 + col) * NORI + p0) * NG;
    u16x4 x0[4];
#pragma unroll
    for (int j = 0; j < 4; ++j) x0[j] = *(const u16x4*)&g0[j * 128 + hx0];
    fill(1, 1); fill(2, 2); fill(3, 3); fill(4, 4); fill(5, 5);
#pragma unroll
    for (int j = 0; j < 4; ++j) {
      accN[j][0] = bf2f(x0[j][0]); accN[j][1] = bf2f(x0[j][1]);
      accN[j][2] = bf2f(x0[j][2]); accN[j][3] = bf2f(x0[j][3]);
    }
  }
  __syncthreads();   // drains all prologue DMAs (compiler emits vmcnt(0))

  long hbase = ((long)(b0 + col) * NORI) * HID;

  for (int s = 0; s < n; ++s) {
    int cur = s & 1, nxt = cur ^ 1;
    fill(s + 6, s % 6);          // overwrites x(s): read last iter, barrier-safe
    short8 bfr[4];
#pragma unroll
    for (int kf = 0; kf < 4; ++kf) bfr[kf] = *(const short8*)&HS[cur][col][kf * 32 + quad * 8];
    f32x4 acc[4];
#pragma unroll
    for (int j = 0; j < 4; ++j) acc[j] = accN[j];
#pragma unroll
    for (int kf = 0; kf < 4; ++kf) {
#pragma unroll
      for (int j = 0; j < 4; ++j)
        acc[j] = __builtin_amdgcn_mfma_f32_16x16x32_bf16(afr[j][kf], bfr[kf], acc[j], 0, 0, 0);
    }
    u16x4 xn[4];
    {
      int sl1 = (s + 1) % 6;
#pragma unroll
      for (int j = 0; j < 4; ++j) xn[j] = *(const u16x4*)&XS[sl1][col][j * 128 + hx0];
    }
    u16x4 hq;
#pragma unroll
    for (int r = 0; r < 4; ++r) {
      float A  = e2(acc[0][r]);
      float Fv = e2(acc[1][r]);
      float G  = e2(acc[2][r]);
      float O  = e2(acc[3][r]);
      float is_ = rcp_(1.f + A);
      float fs_ = rcp_(1.f + Fv);
      float tg  = 1.f - 2.f * rcp_(1.f + G);
      float cn  = fs_ * c[r] + is_ * tg;
      c[r] = cn;
      float C2  = e2(cn * (2.f * L2E));
      float tc  = 1.f - 2.f * rcp_(1.f + C2);
      hq[r] = f2bf(rcp_(1.f + O) * tc);
    }
#pragma unroll
    for (int j = 0; j < 4; ++j) {
      accN[j][0] = bf2f(xn[j][0]); accN[j][1] = bf2f(xn[j][1]);
      accN[j][2] = bf2f(xn[j][2]); accN[j][3] = bf2f(xn[j][3]);
    }
    int p = posAt(s);
    *(u16x4*)&hout[hbase + (long)p * HID + hx0] = hq;   // normal store: h is consumed by ori
    *(u16x4*)&HS[nxt][col][hx0] = hq;
    asm volatile("s_waitcnt vmcnt(13) lgkmcnt(0)\ns_barrier" ::: "memory");
  }
  asm volatile("s_waitcnt vmcnt(0)" ::: "memory");  // no DMA in flight at exit
}

// ---- standalone xp level-0 (feeds LSTM level-0 immediately) ----
__launch_bounds__(512, 2)
__global__ void k_xp0(const unsigned short* __restrict__ embbf,
                      const unsigned short* __restrict__ wihf, const unsigned short* __restrict__ wihb,
                      const float* __restrict__ bfp, const float* __restrict__ bbp,
                      unsigned short* __restrict__ xpf, unsigned short* __restrict__ xpb) {
  __shared__ __align__(16) char smem_[36864];
  body_xp(smem_, threadIdx.x, blockIdx.x * 2, 0, embbf, wihf, wihb, bfp, bbp, xpf, xpb);
}

// 2x-coarsened gate counts
__device__ __forceinline__ int cmbCnt(int l) { return (128 >> l) * 2; }
__device__ __forceinline__ int xpCnt(int l)  { return (256 >> l) * 4; }

// segment tables: type 0=cmb(4 tiles/task), 1=xp(4 tiles/task), 2=jnt, 3=ori, 4=lstm
__device__ const unsigned short g_segN[30] = {256,512,8, 128,256,8, 64,128,8, 32,64,8,
                                              16,32,8, 8,16,8, 4,8,8, 501,
                                              8,16,32,64,128,256,512,1024};
__device__ const unsigned char g_segT[30] = {0,1,4, 0,1,4, 0,1,4, 0,1,4, 0,1,4, 0,1,4, 0,1,4, 2,
                                             3,3,3,3,3,3,3,3};
__device__ const unsigned char g_segL[30] = {0,1,1, 1,2,2, 2,3,3, 3,4,4, 4,5,5, 5,6,6, 6,7,7, 0,
                                             7,6,5,4,3,2,1,0};

// ---- persistent mega kernel ----
// blocks 0-7: LSTM level-0 chains (zero waits -> cannot deadlock).
// blocks 8+: ticketed task queue; deps point to strictly-earlier tickets.
__launch_bounds__(512, 1)
__global__ void k_mega(unsigned short* __restrict__ xpf, unsigned short* __restrict__ xpb,
                       const unsigned short* __restrict__ whhf, const unsigned short* __restrict__ whhb,
                       const float* __restrict__ h0f, const float* __restrict__ c0f,
                       unsigned short* __restrict__ hf, unsigned short* __restrict__ hb,
                       unsigned short* __restrict__ embbf,
                       const unsigned short* __restrict__ wihf, const unsigned short* __restrict__ wihb,
                       const float* __restrict__ bfp, const float* __restrict__ bbp,
                       const unsigned short* __restrict__ wcmbT,
                       const unsigned short* __restrict__ wc0T, const unsigned short* __restrict__ wc1T,
                       const float* __restrict__ bcmb, const float* __restrict__ bcnv,
                       const float* __restrict__ wjnt, const float* __restrict__ bjnt,
                       const float* __restrict__ wori, const float* __restrict__ bori,
                       const int* __restrict__ lhsA, const int* __restrict__ rhsA,
                       const int* __restrict__ jntA,
                       void* __restrict__ outp, const int* __restrict__ flag,
                       int* __restrict__ sync) {
  __shared__ __align__(16) char smem_[108544];
  __shared__ int s_task;
  int tid = threadIdx.x;
  int bid = blockIdx.x;

  if (bid < 8) {                      // dedicated LSTM level-0; no waits at all
    body_lstm(smem_, tid, bid, xpf, xpb, whhf, whhb, h0f, c0f, hf, hb);
    __syncthreads();
    if (tid == 0) release_add(syncp(sync, SY_H + 0));
    return;
  }

  int fm = *flag;
  int gseg = -1, gjcmb = -1;
  for (;;) {
    __syncthreads();
    if (tid == 0)
      s_task = (int)__hip_atomic_fetch_add(syncp(sync, SY_TICKET), 1,
                                           __ATOMIC_RELAXED, __HIP_MEMORY_SCOPE_AGENT);
    __syncthreads();
    int t = s_task;
    if (t >= NTASK) return;
    int seg = 0;
    while (t >= g_segN[seg]) { t -= g_segN[seg]; ++seg; }
    int typ = g_segT[seg], lv = g_segL[seg];

    if (typ == 0) {                       // combine level lv, 4 tiles
      if (lv > 0 && seg != gseg) acquire_wait(syncp(sync, SY_CMB + lv - 1), cmbCnt(lv - 1));
      gseg = seg;
      body_cmb(smem_, tid, t * 4, lv, embbf, wcmbT, bcmb, lhsA, rhsA, jntA, outp, embbf, fm);
      body_cmb(smem_, tid, t * 4 + 2, lv, embbf, wcmbT, bcmb, lhsA, rhsA, jntA, outp, embbf, fm);
      __syncthreads();
      if (tid == 0) release_add(syncp(sync, SY_CMB + lv));
    } else if (typ == 1) {                // xp level lv (lv >= 1), 4 tiles
      if (seg != gseg) acquire_wait(syncp(sync, SY_CMB + lv - 1), cmbCnt(lv - 1));
      gseg = seg;
      body_xp(smem_, tid, t * 4, lv, embbf, wihf, wihb, bfp, bbp, xpf, xpb);
      body_xp(smem_, tid, t * 4 + 2, lv, embbf, wihf, wihb, bfp, bbp, xpf, xpb);
      __syncthreads();
      if (tid == 0) release_add(syncp(sync, SY_XP + lv));
    } else if (typ == 4) {                // LSTM chain, level lv (lv >= 1)
      if (seg != gseg) acquire_wait(syncp(sync, SY_XP + lv), xpCnt(lv));
      gseg = seg;
      body_lstm(smem_, tid, 8 * lv + t, xpf, xpb, whhf, whhb, h0f, c0f, hf, hb);
      __syncthreads();
      if (tid == 0) release_add(syncp(sync, SY_H + lv));
    } else if (typ == 2) {                // joint group t
      int lmax;
      {
        int jf = t * 64, jl = t * 64 + 63;
        int bf_ = jf / 501, bl_ = jl / 501;
        int jr = (bf_ == bl_) ? (jl - bl_ * 501) : 500;
        const int joffs[8] = {0, 255, 382, 445, 476, 491, 498, 501};
        int l = 0;
        while (l < 6 && jr >= joffs[l + 1]) ++l;
        lmax = l;
      }
      if (lmax - 1 > gjcmb) {             // cmb levels complete in order -> monotone cache
        acquire_wait(syncp(sync, SY_CMB + lmax - 1), cmbCnt(lmax - 1));
        gjcmb = lmax - 1;
      }
      body_jnt(smem_, tid, t, embbf, wc0T, wc1T, bcnv, wjnt, bjnt, outp, fm);
    } else {                              // ori level lv, chunk t
      if (seg != gseg) acquire_wait(syncp(sync, SY_H + lv), 8);
      gseg = seg;
      body_ori(tid, t, lv, hf, hb, wori, bori, outp, fm);
    }
  }
}

extern "C" void kernel_launch(void* const* d_in, const int* in_sizes, int n_in,
                              void* d_out, int out_size, void* d_ws, size_t ws_size,
                              hipStream_t stream) {
  (void)in_sizes; (void)n_in; (void)out_size;
  const void* unit_emb  = d_in[0];
  const void* existence = d_in[1];
  const void* sright    = d_in[2];
  const void* sjoint    = d_in[3];
  const void* h0        = d_in[4];
  const void* c0        = d_in[5];
  const void* wih_f     = d_in[6];
  const void* whh_f     = d_in[7];
  const void* b_f       = d_in[8];
  const void* wih_b     = d_in[9];
  const void* whh_b     = d_in[10];
  const void* b_b       = d_in[11];
  const void* w_ori     = d_in[12];
  const void* b_ori     = d_in[13];
  const void* w_cnv     = d_in[14];
  const void* b_cnv     = d_in[15];
  const void* w_jnt     = d_in[16];
  const void* b_jnt     = d_in[17];
  const void* w_cmb     = d_in[18];
  const void* b_cmb     = d_in[19];

  char* wsb = (char*)d_ws;
  size_t off = 0;
  auto alloc = [&](size_t bytes) -> void* {
    void* r = wsb + off;
    off += (bytes + 255) & ~(size_t)255;
    return r;
  };
  int* flag = (int*)alloc(sizeof(int));
  int* sync = (int*)alloc(4096 * sizeof(int));   // 64 counters x 256B padding
  unsigned short* embbf = (unsigned short*)alloc((size_t)B * NORI * DM * 2);
  unsigned short* xpf   = (unsigned short*)alloc((size_t)B * NORI * NG * 2);
  unsigned short* xpb   = (unsigned short*)alloc((size_t)B * NORI * NG * 2);
  unsigned short* hfb   = (unsigned short*)alloc((size_t)B * NORI * HID * 2);
  unsigned short* hbb   = (unsigned short*)alloc((size_t)B * NORI * HID * 2);
  unsigned short* wihf  = (unsigned short*)alloc(512 * 512 * 2);
  unsigned short* wihb  = (unsigned short*)alloc(512 * 512 * 2);
  unsigned short* whhfb = (unsigned short*)alloc(512 * 128 * 2);
  unsigned short* whhbb = (unsigned short*)alloc(512 * 128 * 2);
  unsigned short* wcmbT = (unsigned short*)alloc(512 * 1024 * 2);
  unsigned short* wc0T  = (unsigned short*)alloc(256 * 512 * 2);
  unsigned short* wc1T  = (unsigned short*)alloc(256 * 512 * 2);
  float* bf32   = (float*)alloc(512 * 4);
  float* bb32   = (float*)alloc(512 * 4);
  float* bcnv32 = (float*)alloc(256 * 4);
  float* bori32 = (float*)alloc(2 * 4);
  float* bjnt32 = (float*)alloc(1 * 4);
  float* bcmb32 = (float*)alloc(512 * 4);
  float* wori32 = (float*)alloc(512 * 4);
  float* wjnt32 = (float*)alloc(256 * 4);
  float* h0f    = (float*)alloc(256 * 4);
  float* c0f    = (float*)alloc(256 * 4);
  int* lhsA = (int*)alloc((size_t)7 * B * 128 * 4);
  int* rhsA = (int*)alloc((size_t)7 * B * 128 * 4);
  int* jntA = (int*)alloc((size_t)7 * B * 128 * 4);
  if (off > ws_size) return;

  k_detect<<<1, 256, 0, stream>>>((const unsigned int*)unit_emb, flag);
  k_prep_all<<<38990, 256, 0, stream>>>(unit_emb, sright, sjoint, existence,
                                        wih_f, wih_b, whh_f, whh_b, w_cmb, w_cnv,
                                        b_f, b_b, b_cnv, b_ori, b_jnt, b_cmb, w_ori, w_jnt, h0, c0,
                                        wihf, wihb, whhfb, whhbb, wcmbT, wc0T, wc1T,
                                        bf32, bb32, bcnv32, bori32, bjnt32, bcmb32, wori32, wjnt32,
                                        h0f, c0f, d_out, embbf, lhsA, rhsA, jntA, flag, sync);
  k_xp0<<<2048, 512, 0, stream>>>(embbf, wihf, wihb, bf32, bb32, xpf, xpb);
  k_mega<<<256, 512, 0, stream>>>(xpf, xpb, whhfb, whhbb, h0f, c0f, hfb, hbb, embbf,
                                  wihf, wihb, bf32, bb32, wcmbT, wc0T, wc1T,
                                  bcmb32, bcnv32, wjnt32, bjnt32, wori32, bori32,
                                  lhsA, rhsA, jntA, d_out, flag, sync);
}